// Round 4
// baseline (1397.803 us; speedup 1.0000x reference)
//
#include <hip/hip_runtime.h>
#include <math.h>

// CEpsilonLoss: out = -mean(V) + mean_i( log( mean_j exp((V[j] - c[i,j]) * eps) ) ) / eps
// c[i,j] = sum_d |A[i,d] - B[j,d]|  -- FP32 VALU-bound (|a-b| not bilinear -> no MFMA).
// Floor: N*M*D*2 lane-ops / 78.6e12 = ~109 us.
//
// v4: plain loads + linear ds_write_b128 staging (zero write conflicts, zero
// transpose movs). LDS is [row][32 floats] with float4-chunk XOR swizzle
// phys = c ^ ((row>>3 ^ row)&7), realized by pre-permuting the per-lane GLOBAL
// source chunk so the LDS store stays linear; reads apply the same XOR.
// Register-staged double buffer, 1 barrier/tile, compile-time LDS ping-pong.

#define D_DIM 1024
#define BI 128   // rows (real) per block
#define BJ 64    // cols (fake) per block
#define BK 32    // k-tile (8 float4 chunks per row)
#define TI 8     // per-thread rows
#define TJ 4     // per-thread cols

__global__ __launch_bounds__(256, 2)
void ceps_cdist_partial(const float* __restrict__ A,
                        const float* __restrict__ B,
                        const float* __restrict__ V,
                        float* __restrict__ pmax,   // [N][M/BJ]
                        float* __restrict__ psums,  // [N][M/BJ]
                        int N, int M)
{
    __shared__ float As[2][BI * BK];   // 2 x 16 KB
    __shared__ float Bs[2][BJ * BK];   // 2 x  8 KB

    const int t    = threadIdx.x;
    const int tx   = t & 15;           // j group: B rows tx*4..tx*4+3
    const int ty   = t >> 4;           // i group: A rows ty*8..ty*8+7
    const int row8 = t >> 3;           // 0..31 staging row base
    const int chk  = t & 7;            // 0..7  staging float4 chunk (physical)

    // XCD-chunked swizzle: each XCD gets an 8x8 (ib x jb) sub-grid -> ~6MB WS
    const int nib = N / BI, njb = M / BJ;
    const int bid = blockIdx.x;
    int ib, jb;
    if (nib == 16 && njb == 32) {
        ib = ((bid & 1) << 3) | ((bid >> 3) & 7);
        jb = (((bid >> 1) & 3) << 3) | (bid >> 6);
    } else {
        jb = bid % njb; ib = bid / njb;
    }
    const int i0 = ib * BI, j0 = jb * BJ;
    const int MB = njb;

    // swizzle keys: key(row) = ((row>>3) ^ row) & 7
    const int kA0 = ((row8 >> 3) ^ (row8 & 7)) & 7;     // staging key (u even); u odd: ^4
    const int ka  = ty & 7;                             // A-read key (rows ty*8+r -> key = ka^r)
    const int kb0 = ((tx >> 1) ^ ((tx & 1) << 2)) & 7;  // B-read key (rows tx*4+s -> key = kb0^s)

    // pre-permuted global sources (so LDS stores are LINEAR)
    const float* pa0 = A + (size_t)(i0 + row8 +  0) * D_DIM + 4 * (chk ^ kA0);
    const float* pa1 = A + (size_t)(i0 + row8 + 32) * D_DIM + 4 * (chk ^ kA0 ^ 4);
    const float* pa2 = A + (size_t)(i0 + row8 + 64) * D_DIM + 4 * (chk ^ kA0);
    const float* pa3 = A + (size_t)(i0 + row8 + 96) * D_DIM + 4 * (chk ^ kA0 ^ 4);
    const float* pb0 = B + (size_t)(j0 + row8 +  0) * D_DIM + 4 * (chk ^ kA0);
    const float* pb1 = B + (size_t)(j0 + row8 + 32) * D_DIM + 4 * (chk ^ kA0 ^ 4);

    float4 ra0, ra1, ra2, ra3, rb0, rb1;
    auto loadreg = [&]() {
        ra0 = *(const float4*)pa0;  ra1 = *(const float4*)pa1;
        ra2 = *(const float4*)pa2;  ra3 = *(const float4*)pa3;
        rb0 = *(const float4*)pb0;  rb1 = *(const float4*)pb1;
        pa0 += BK; pa1 += BK; pa2 += BK; pa3 += BK; pb0 += BK; pb1 += BK;
    };

    auto store = [&](float* Ad, float* Bd) {
        *(float4*)&Ad[(row8 +  0) * BK + 4 * chk] = ra0;   // linear 1KB/wave sweeps
        *(float4*)&Ad[(row8 + 32) * BK + 4 * chk] = ra1;
        *(float4*)&Ad[(row8 + 64) * BK + 4 * chk] = ra2;
        *(float4*)&Ad[(row8 + 96) * BK + 4 * chk] = ra3;
        *(float4*)&Bd[(row8 +  0) * BK + 4 * chk] = rb0;
        *(float4*)&Bd[(row8 + 32) * BK + 4 * chk] = rb1;
    };

    float acc[TI][TJ];
    #pragma unroll
    for (int r = 0; r < TI; ++r)
        #pragma unroll
        for (int s = 0; s < TJ; ++s) acc[r][s] = 0.0f;

    auto compute = [&](const float* Asb, const float* Bsb) {
        const float* Ab = Asb + (ty * TI) * BK;
        const float* Bb = Bsb + (tx * TJ) * BK;
        #pragma unroll
        for (int c = 0; c < 8; ++c) {
            float4 b0 = *(const float4*)&Bb[0 * BK + (((c ^ 0) ^ kb0) << 2)];
            float4 b1 = *(const float4*)&Bb[1 * BK + (((c ^ 1) ^ kb0) << 2)];
            float4 b2 = *(const float4*)&Bb[2 * BK + (((c ^ 2) ^ kb0) << 2)];
            float4 b3 = *(const float4*)&Bb[3 * BK + (((c ^ 3) ^ kb0) << 2)];
            #pragma unroll
            for (int r = 0; r < TI; ++r) {
                float4 a = *(const float4*)&Ab[r * BK + (((c ^ r) ^ ka) << 2)];
                acc[r][0] += fabsf(a.x - b0.x);
                acc[r][0] += fabsf(a.y - b0.y);
                acc[r][0] += fabsf(a.z - b0.z);
                acc[r][0] += fabsf(a.w - b0.w);
                acc[r][1] += fabsf(a.x - b1.x);
                acc[r][1] += fabsf(a.y - b1.y);
                acc[r][1] += fabsf(a.z - b1.z);
                acc[r][1] += fabsf(a.w - b1.w);
                acc[r][2] += fabsf(a.x - b2.x);
                acc[r][2] += fabsf(a.y - b2.y);
                acc[r][2] += fabsf(a.z - b2.z);
                acc[r][2] += fabsf(a.w - b2.w);
                acc[r][3] += fabsf(a.x - b3.x);
                acc[r][3] += fabsf(a.y - b3.y);
                acc[r][3] += fabsf(a.z - b3.z);
                acc[r][3] += fabsf(a.w - b3.w);
            }
        }
    };

    // tile 0
    loadreg();
    store(As[0], Bs[0]);
    __syncthreads();

    #pragma unroll 1
    for (int i = 0; i < 15; ++i) {
        loadreg();                   // tile 2i+1 in flight during compute
        compute(As[0], Bs[0]);
        store(As[1], Bs[1]);
        __syncthreads();
        loadreg();                   // tile 2i+2
        compute(As[1], Bs[1]);
        store(As[0], Bs[0]);
        __syncthreads();
    }
    loadreg();                       // tile 31
    compute(As[0], Bs[0]);
    store(As[1], Bs[1]);
    __syncthreads();
    compute(As[1], Bs[1]);

    // epilogue: x = (V[j] - c) * eps; stable block-local max + sum(exp(x - max))
    const float eps = 0.1f;
    float vj[TJ];
    #pragma unroll
    for (int s = 0; s < TJ; ++s) vj[s] = V[j0 + tx * TJ + s];

    #pragma unroll
    for (int r = 0; r < TI; ++r) {
        float x[TJ];
        #pragma unroll
        for (int s = 0; s < TJ; ++s) x[s] = (vj[s] - acc[r][s]) * eps;

        float m = fmaxf(fmaxf(x[0], x[1]), fmaxf(x[2], x[3]));
        m = fmaxf(m, __shfl_xor(m, 1));
        m = fmaxf(m, __shfl_xor(m, 2));
        m = fmaxf(m, __shfl_xor(m, 4));
        m = fmaxf(m, __shfl_xor(m, 8));

        float p = 0.0f;
        #pragma unroll
        for (int s = 0; s < TJ; ++s) p += expf(x[s] - m);
        p += __shfl_xor(p, 1);
        p += __shfl_xor(p, 2);
        p += __shfl_xor(p, 4);
        p += __shfl_xor(p, 8);

        if (tx == 0) {
            const int row = i0 + ty * TI + r;
            pmax [row * MB + jb] = m;
            psums[row * MB + jb] = p;
        }
    }
}

__global__ void ceps_row_logmean(const float* __restrict__ pmax,
                                 const float* __restrict__ psums,
                                 float* __restrict__ lrow,
                                 int N, int M)
{
    const int MB = M / BJ;
    int i = blockIdx.x * blockDim.x + threadIdx.x;
    if (i < N) {
        float m = -INFINITY;
        for (int jb = 0; jb < MB; ++jb) m = fmaxf(m, pmax[i * MB + jb]);
        float s = 0.0f;
        for (int jb = 0; jb < MB; ++jb)
            s += psums[i * MB + jb] * expf(pmax[i * MB + jb] - m);
        lrow[i] = m + logf(s) - logf((float)M);
    }
}

__global__ void ceps_final(const float* __restrict__ lrow,
                           const float* __restrict__ V,
                           float* __restrict__ out,
                           int N, int M)
{
    __shared__ float sl[256];
    __shared__ float sv[256];
    int t = threadIdx.x;
    float a = 0.0f, b = 0.0f;
    for (int i = t; i < N; i += 256) a += lrow[i];
    for (int i = t; i < M; i += 256) b += V[i];
    sl[t] = a; sv[t] = b;
    __syncthreads();
    for (int o = 128; o > 0; o >>= 1) {
        if (t < o) { sl[t] += sl[t + o]; sv[t] += sv[t + o]; }
        __syncthreads();
    }
    if (t == 0) {
        float fake_term = sv[0] / (float)M;
        float mean_log  = sl[0] / (float)N;
        out[0] = -fake_term + mean_log / 0.1f;
    }
}

extern "C" void kernel_launch(void* const* d_in, const int* in_sizes, int n_in,
                              void* d_out, int out_size, void* d_ws, size_t ws_size,
                              hipStream_t stream) {
    const float* A = (const float*)d_in[0];   // real_objects [N,1024]
    const float* B = (const float*)d_in[1];   // fake_objects [M,1024]
    const float* V = (const float*)d_in[2];   // fake_validity [M]

    const int N = in_sizes[0] / D_DIM;   // 2048
    const int M = in_sizes[1] / D_DIM;   // 2048
    const int MB = M / BJ;               // 32

    float* pmax  = (float*)d_ws;
    float* psums = pmax + (size_t)N * MB;
    float* lrow  = psums + (size_t)N * MB;

    const int nblocks = (M / BJ) * (N / BI);           // 512
    ceps_cdist_partial<<<nblocks, 256, 0, stream>>>(A, B, V, pmax, psums, N, M);
    ceps_row_logmean<<<(N + 255) / 256, 256, 0, stream>>>(pmax, psums, lrow, N, M);
    ceps_final<<<1, 256, 0, stream>>>(lrow, V, (float*)d_out, N, M);
}

// Round 5
// 320.164 us; speedup vs baseline: 4.3659x; 4.3659x over previous
//
#include <hip/hip_runtime.h>
#include <math.h>

// CEpsilonLoss: out = -mean(V) + mean_i( log( mean_j exp((V[j] - c[i,j]) * eps) ) ) / eps
// c[i,j] = sum_d |A[i,d] - B[j,d]|  -- FP32 VALU-bound (|a-b| not bilinear -> no MFMA).
// Floor: N*M*D*2 lane-ops / 78.6e12 = ~109 us.
//
// v5: LDS i-major [row][32] (same as global layout):
//   - staging = coalesced global float4 + LINEAR ds_write_b128 (no transpose
//     movs, no write bank conflicts)
//   - compute reads are scalar ds_read_b32: A-reads are 16-lane broadcasts,
//     B-reads are float4-chunk XOR-swizzled (key=(row>>2)&7) so the 16 tx
//     groups land on 8 distinct banks (2-way = free). A also swizzled
//     (key=(row>>3)&3) to spread its 4 broadcast groups over 4 banks.
//     Swizzle realized by pre-permuting the per-lane GLOBAL source chunk
//     (linear store + swizzled read). Per-thread read key is CONSTANT.
//   - reg-staged double buffer, 1 barrier/tile, compile-time ping-pong,
//     partial unroll to keep VGPR < 128 (round 3/4 spilled to scratch).

#define D_DIM 1024
#define BI 128   // rows (real) per block
#define BJ 64    // cols (fake) per block
#define BK 32    // k-tile (8 float4 chunks per row)
#define TI 8     // per-thread rows
#define TJ 4     // per-thread cols

__global__ __launch_bounds__(256, 2)
void ceps_cdist_partial(const float* __restrict__ A,
                        const float* __restrict__ B,
                        const float* __restrict__ V,
                        float* __restrict__ pmax,   // [N][M/BJ]
                        float* __restrict__ psums,  // [N][M/BJ]
                        int N, int M)
{
    __shared__ float As[2][BI * BK];   // 2 x 16 KB, i-major
    __shared__ float Bs[2][BJ * BK];   // 2 x  8 KB, i-major

    const int t    = threadIdx.x;
    const int tx   = t & 15;           // j group: B rows tx*4..tx*4+3
    const int ty   = t >> 4;           // i group: A rows ty*8..ty*8+7
    const int row8 = t >> 3;           // 0..31 staging row base
    const int chk  = t & 7;            // 0..7  staging float4 chunk (physical)

    // XCD-chunked block swizzle: each XCD gets an 8x8 (ib x jb) sub-grid
    const int nib = N / BI, njb = M / BJ;
    const int bid = blockIdx.x;
    int ib, jb;
    if (nib == 16 && njb == 32) {
        ib = ((bid & 1) << 3) | ((bid >> 3) & 7);
        jb = (((bid >> 1) & 3) << 3) | (bid >> 6);
    } else {
        jb = bid % njb; ib = bid / njb;
    }
    const int i0 = ib * BI, j0 = jb * BJ;
    const int MB = njb;

    // staging source chunk keys (constant per thread; rows row8+32u share key)
    const int kStA = (row8 >> 3) & 3;   // A: key(row) = (row>>3)&3
    const int kStB = (row8 >> 2) & 7;   // B: key(row) = (row>>2)&7

    const float* pa0 = A + (size_t)(i0 + row8 +  0) * D_DIM + 4 * (chk ^ kStA);
    const float* pa1 = A + (size_t)(i0 + row8 + 32) * D_DIM + 4 * (chk ^ kStA);
    const float* pa2 = A + (size_t)(i0 + row8 + 64) * D_DIM + 4 * (chk ^ kStA);
    const float* pa3 = A + (size_t)(i0 + row8 + 96) * D_DIM + 4 * (chk ^ kStA);
    const float* pb0 = B + (size_t)(j0 + row8 +  0) * D_DIM + 4 * (chk ^ kStB);
    const float* pb1 = B + (size_t)(j0 + row8 + 32) * D_DIM + 4 * (chk ^ kStB);

    // compute-side read keys (constant per thread), float-granular (key<<2)
    const int kA4 = (ty & 3) << 2;
    const int kB4 = (tx & 7) << 2;

    float4 ra0, ra1, ra2, ra3, rb0, rb1;

#define LOADREG                                                   \
    do {                                                          \
        ra0 = *(const float4*)pa0;  ra1 = *(const float4*)pa1;    \
        ra2 = *(const float4*)pa2;  ra3 = *(const float4*)pa3;    \
        rb0 = *(const float4*)pb0;  rb1 = *(const float4*)pb1;    \
        pa0 += BK; pa1 += BK; pa2 += BK; pa3 += BK;               \
        pb0 += BK; pb1 += BK;                                     \
    } while (0)

#define STORE(BUF)                                                \
    do {                                                          \
        *(float4*)&As[BUF][(row8 +  0) * BK + 4 * chk] = ra0;     \
        *(float4*)&As[BUF][(row8 + 32) * BK + 4 * chk] = ra1;     \
        *(float4*)&As[BUF][(row8 + 64) * BK + 4 * chk] = ra2;     \
        *(float4*)&As[BUF][(row8 + 96) * BK + 4 * chk] = ra3;     \
        *(float4*)&Bs[BUF][(row8 +  0) * BK + 4 * chk] = rb0;     \
        *(float4*)&Bs[BUF][(row8 + 32) * BK + 4 * chk] = rb1;     \
    } while (0)

    float acc[TI][TJ];
    #pragma unroll
    for (int r = 0; r < TI; ++r)
        #pragma unroll
        for (int s = 0; s < TJ; ++s) acc[r][s] = 0.0f;

#define COMPUTE(BUF)                                              \
    do {                                                          \
        const float* Ab = &As[BUF][ty * TI * BK];                 \
        const float* Bb = &Bs[BUF][tx * TJ * BK];                 \
        _Pragma("unroll 8")                                       \
        for (int kk = 0; kk < BK; ++kk) {                         \
            const int fa = kk ^ kA4;                              \
            const int fb = kk ^ kB4;                              \
            float bv[TJ], av[TI];                                 \
            _Pragma("unroll")                                     \
            for (int s = 0; s < TJ; ++s) bv[s] = Bb[s * BK + fb]; \
            _Pragma("unroll")                                     \
            for (int r = 0; r < TI; ++r) av[r] = Ab[r * BK + fa]; \
            _Pragma("unroll")                                     \
            for (int r = 0; r < TI; ++r) {                        \
                _Pragma("unroll")                                 \
                for (int s = 0; s < TJ; ++s)                      \
                    acc[r][s] += fabsf(av[r] - bv[s]);            \
            }                                                     \
        }                                                         \
    } while (0)

    // 32 k-tiles, double-buffered, one barrier per tile
    LOADREG;                 // tile 0
    STORE(0);
    __syncthreads();

    #pragma unroll 1
    for (int it = 0; it < 15; ++it) {
        LOADREG;             // tile 2it+1 (in flight during compute)
        COMPUTE(0);
        STORE(1);
        __syncthreads();
        LOADREG;             // tile 2it+2
        COMPUTE(1);
        STORE(0);
        __syncthreads();
    }
    LOADREG;                 // tile 31
    COMPUTE(0);
    STORE(1);
    __syncthreads();
    COMPUTE(1);

    // epilogue: x = (V[j] - c) * eps; stable block-local max + sum(exp(x - max))
    const float eps = 0.1f;
    float vj[TJ];
    #pragma unroll
    for (int s = 0; s < TJ; ++s) vj[s] = V[j0 + tx * TJ + s];

    #pragma unroll
    for (int r = 0; r < TI; ++r) {
        float x[TJ];
        #pragma unroll
        for (int s = 0; s < TJ; ++s) x[s] = (vj[s] - acc[r][s]) * eps;

        float m = fmaxf(fmaxf(x[0], x[1]), fmaxf(x[2], x[3]));
        m = fmaxf(m, __shfl_xor(m, 1));
        m = fmaxf(m, __shfl_xor(m, 2));
        m = fmaxf(m, __shfl_xor(m, 4));
        m = fmaxf(m, __shfl_xor(m, 8));

        float p = 0.0f;
        #pragma unroll
        for (int s = 0; s < TJ; ++s) p += expf(x[s] - m);
        p += __shfl_xor(p, 1);
        p += __shfl_xor(p, 2);
        p += __shfl_xor(p, 4);
        p += __shfl_xor(p, 8);

        if (tx == 0) {
            const int row = i0 + ty * TI + r;
            pmax [row * MB + jb] = m;
            psums[row * MB + jb] = p;
        }
    }
#undef LOADREG
#undef STORE
#undef COMPUTE
}

__global__ void ceps_row_logmean(const float* __restrict__ pmax,
                                 const float* __restrict__ psums,
                                 float* __restrict__ lrow,
                                 int N, int M)
{
    const int MB = M / BJ;
    int i = blockIdx.x * blockDim.x + threadIdx.x;
    if (i < N) {
        float m = -INFINITY;
        for (int jb = 0; jb < MB; ++jb) m = fmaxf(m, pmax[i * MB + jb]);
        float s = 0.0f;
        for (int jb = 0; jb < MB; ++jb)
            s += psums[i * MB + jb] * expf(pmax[i * MB + jb] - m);
        lrow[i] = m + logf(s) - logf((float)M);
    }
}

__global__ void ceps_final(const float* __restrict__ lrow,
                           const float* __restrict__ V,
                           float* __restrict__ out,
                           int N, int M)
{
    __shared__ float sl[256];
    __shared__ float sv[256];
    int t = threadIdx.x;
    float a = 0.0f, b = 0.0f;
    for (int i = t; i < N; i += 256) a += lrow[i];
    for (int i = t; i < M; i += 256) b += V[i];
    sl[t] = a; sv[t] = b;
    __syncthreads();
    for (int o = 128; o > 0; o >>= 1) {
        if (t < o) { sl[t] += sl[t + o]; sv[t] += sv[t + o]; }
        __syncthreads();
    }
    if (t == 0) {
        float fake_term = sv[0] / (float)M;
        float mean_log  = sl[0] / (float)N;
        out[0] = -fake_term + mean_log / 0.1f;
    }
}

extern "C" void kernel_launch(void* const* d_in, const int* in_sizes, int n_in,
                              void* d_out, int out_size, void* d_ws, size_t ws_size,
                              hipStream_t stream) {
    const float* A = (const float*)d_in[0];   // real_objects [N,1024]
    const float* B = (const float*)d_in[1];   // fake_objects [M,1024]
    const float* V = (const float*)d_in[2];   // fake_validity [M]

    const int N = in_sizes[0] / D_DIM;   // 2048
    const int M = in_sizes[1] / D_DIM;   // 2048
    const int MB = M / BJ;               // 32

    float* pmax  = (float*)d_ws;
    float* psums = pmax + (size_t)N * MB;
    float* lrow  = psums + (size_t)N * MB;

    const int nblocks = (M / BJ) * (N / BI);           // 512
    ceps_cdist_partial<<<nblocks, 256, 0, stream>>>(A, B, V, pmax, psums, N, M);
    ceps_row_logmean<<<(N + 255) / 256, 256, 0, stream>>>(pmax, psums, lrow, N, M);
    ceps_final<<<1, 256, 0, stream>>>(lrow, V, (float*)d_out, N, M);
}